// Round 3
// baseline (40803.613 us; speedup 1.0000x reference)
//
#include <hip/hip_runtime.h>

#define KK 27
#define NPTS 1000000
#define C 16

__device__ __forceinline__ double elu64(double x) { return x > 0.0 ? x : expm1(x); }

__device__ __forceinline__ void atomAddF64(double* p, double v) {
#if defined(__gfx90a__) || defined(__gfx940__) || defined(__gfx941__) || defined(__gfx942__) || defined(__gfx950__)
    unsafeAtomicAdd(p, v);   // native global_atomic_add_f64 (coarse-grained mem)
#else
    atomicAdd(p, v);
#endif
}

// ---------------- conv1: Cin=1 scatter, f64 accumulate ----------------
__global__ void __launch_bounds__(256) conv1_f64(
    const float* __restrict__ feats, const float* __restrict__ W1,
    const int* __restrict__ in_map, const int* __restrict__ out_map,
    double* __restrict__ out1)
{
    const int k = blockIdx.y;
    __shared__ double w[C];
    if (threadIdx.x < C) w[threadIdx.x] = (double)W1[k * C + threadIdx.x];
    __syncthreads();
    const int i = blockIdx.x * 256 + threadIdx.x;
    if (i >= NPTS) return;
    const int base = k * NPTS + i;
    const double v = (double)feats[in_map[base]];
    double* o = out1 + (size_t)out_map[base] * C;
#pragma unroll
    for (int c = 0; c < C; ++c) atomAddF64(o + c, v * w[c]);
}

// ---------------- BN stats: f64 sum and sumsq per channel ----------------
__global__ void __launch_bounds__(256) bn_stats_f64(
    const double* __restrict__ x, double* __restrict__ stats)
{
    double s[C], s2[C];
#pragma unroll
    for (int c = 0; c < C; ++c) { s[c] = 0.0; s2[c] = 0.0; }
    const int stride = gridDim.x * 256;
    for (int i = blockIdx.x * 256 + threadIdx.x; i < NPTS; i += stride) {
        const double2* rp = (const double2*)(x + (size_t)i * C);
        double v[C];
#pragma unroll
        for (int j = 0; j < 8; ++j) { double2 d = rp[j]; v[2*j] = d.x; v[2*j+1] = d.y; }
#pragma unroll
        for (int c = 0; c < C; ++c) { s[c] += v[c]; s2[c] += v[c] * v[c]; }
    }
#pragma unroll
    for (int c = 0; c < C; ++c) {
#pragma unroll
        for (int off = 32; off > 0; off >>= 1) {
            s[c]  += __shfl_down(s[c],  off, 64);
            s2[c] += __shfl_down(s2[c], off, 64);
        }
    }
    if ((threadIdx.x & 63) == 0) {
#pragma unroll
        for (int c = 0; c < C; ++c) {
            atomAddF64(&stats[c], s[c]);
            atomAddF64(&stats[C + c], s2[c]);
        }
    }
}

// ---------------- BN + ELU apply; either f64 in-place or round to f32 ----------------
template<bool TO_F32>
__global__ void __launch_bounds__(256) bn_apply(
    double* __restrict__ x, float* __restrict__ out32,
    const double* __restrict__ stats,
    const float* __restrict__ gamma, const float* __restrict__ beta)
{
    __shared__ double sc[C], sh[C];
    if (threadIdx.x < C) {
        const int c = threadIdx.x;
        const double m = stats[c] / (double)NPTS;
        const double v = stats[C + c] / (double)NPTS - m * m;
        const double scale = (double)gamma[c] * rsqrt(v + 1e-5);
        sc[c] = scale;
        sh[c] = (double)beta[c] - m * scale;
    }
    __syncthreads();
    const size_t t = (size_t)blockIdx.x * 256 + threadIdx.x;   // element over N*C
    if (t >= (size_t)NPTS * C) return;
    const int c = (int)(t & (C - 1));
    const double a = elu64(x[t] * sc[c] + sh[c]);
    if (TO_F32) out32[t] = (float)a;
    else        x[t] = a;
}

// ---------------- conv2: 16->16 gather-GEMM-scatter, f64 ----------------
template<typename T>
__global__ void __launch_bounds__(256) conv2_f64(
    const T* __restrict__ h, const float* __restrict__ W2,
    const int* __restrict__ in_map, const int* __restrict__ out_map,
    double* __restrict__ out2)
{
    const int k = blockIdx.y;
    __shared__ double w[C * C];
    w[threadIdx.x] = (double)W2[k * C * C + threadIdx.x];
    __syncthreads();
    const int i = blockIdx.x * 256 + threadIdx.x;
    if (i >= NPTS) return;
    const int base = k * NPTS + i;
    const T* hp = h + (size_t)in_map[base] * C;
    double hv[C];
#pragma unroll
    for (int c = 0; c < C; ++c) hv[c] = (double)hp[c];
    double g[C];
#pragma unroll
    for (int c2 = 0; c2 < C; ++c2) g[c2] = 0.0;
#pragma unroll
    for (int c1 = 0; c1 < C; ++c1) {
        const double hc = hv[c1];
#pragma unroll
        for (int c2 = 0; c2 < C; ++c2) g[c2] += hc * w[c1 * C + c2];
    }
    double* o = out2 + (size_t)out_map[base] * C;
#pragma unroll
    for (int c2 = 0; c2 < C; ++c2) atomAddF64(o + c2, g[c2]);
}

// ---------------- final: BN2 + ELU + cls + prune, f64 -> f32 out ----------------
__global__ void __launch_bounds__(256) final_f64(
    const double* __restrict__ x, const double* __restrict__ stats,
    const float* __restrict__ gamma, const float* __restrict__ beta,
    const float* __restrict__ Wcls, const float* __restrict__ bcls,
    float* __restrict__ out)
{
    __shared__ double sc[C], sh[C], wc[C];
    __shared__ double bc;
    if (threadIdx.x < C) {
        const int c = threadIdx.x;
        const double m = stats[c] / (double)NPTS;
        const double v = stats[C + c] / (double)NPTS - m * m;
        const double scale = (double)gamma[c] * rsqrt(v + 1e-5);
        sc[c] = scale;
        sh[c] = (double)beta[c] - m * scale;
        wc[c] = (double)Wcls[c];
    }
    if (threadIdx.x == 0) bc = (double)bcls[0];
    __syncthreads();
    const int i = blockIdx.x * 256 + threadIdx.x;
    if (i >= NPTS) return;
    const double2* rp = (const double2*)(x + (size_t)i * C);
    double hv[C];
#pragma unroll
    for (int j = 0; j < 8; ++j) { double2 d = rp[j]; hv[2*j] = d.x; hv[2*j+1] = d.y; }
    double hh[C];
    double cls = bc;
#pragma unroll
    for (int c = 0; c < C; ++c) {
        const double e = elu64(hv[c] * sc[c] + sh[c]);
        hh[c] = e;
        cls += e * wc[c];
    }
    const bool keep = cls > 0.0;
    float* row = out + (size_t)i * 17;
#pragma unroll
    for (int c = 0; c < C; ++c) row[c] = keep ? (float)hh[c] : 0.f;
    row[16] = (float)cls;
}

extern "C" void kernel_launch(void* const* d_in, const int* in_sizes, int n_in,
                              void* d_out, int out_size, void* d_ws, size_t ws_size,
                              hipStream_t stream)
{
    const float* feats  = (const float*)d_in[0];
    const float* W1     = (const float*)d_in[1];
    const float* gamma1 = (const float*)d_in[2];
    const float* beta1  = (const float*)d_in[3];
    const float* W2     = (const float*)d_in[4];
    const float* gamma2 = (const float*)d_in[5];
    const float* beta2  = (const float*)d_in[6];
    const float* Wcls   = (const float*)d_in[7];
    const float* bcls   = (const float*)d_in[8];
    const int* in1 = (const int*)d_in[9];
    const int* om1 = (const int*)d_in[10];
    const int* in2 = (const int*)d_in[11];
    const int* om2 = (const int*)d_in[12];

    const size_t BUF = (size_t)NPTS * C;     // 16M elements
    double* bufA = (double*)d_ws;

    const dim3 gconv((NPTS + 255) / 256, KK);
    const int gelem = (int)((BUF + 255) / 256);   // 62500
    const int grow  = (NPTS + 255) / 256;         // 3907

    if (ws_size >= 2 * BUF * 8 + 512) {
        // -------- Plan A: fully f64, two buffers in ws --------
        double* bufB  = bufA + BUF;
        double* stats = bufB + BUF;          // 64 f64 (BN1 at [0:32), BN2 at [32:64))
        hipMemsetAsync(d_ws, 0, 2 * BUF * 8 + 512, stream);
        conv1_f64<<<gconv, 256, 0, stream>>>(feats, W1, in1, om1, bufA);
        bn_stats_f64<<<1024, 256, 0, stream>>>(bufA, stats);
        bn_apply<false><<<gelem, 256, 0, stream>>>(bufA, nullptr, stats, gamma1, beta1);
        conv2_f64<double><<<gconv, 256, 0, stream>>>(bufA, W2, in2, om2, bufB);
        bn_stats_f64<<<1024, 256, 0, stream>>>(bufB, stats + 32);
        final_f64<<<grow, 256, 0, stream>>>(bufB, stats + 32, gamma2, beta2,
                                            Wcls, bcls, (float*)d_out);
    } else {
        // -------- Plan B: single f64 buffer (proven ws >= 128,000,256 B);
        // h1 rounded to f32 staged in d_out[0:64MB] (dead before final writes) --------
        double* stats = (double*)((char*)d_ws + BUF * 8);   // 32 f64 tail
        float* h1 = (float*)d_out;
        hipMemsetAsync(d_ws, 0, BUF * 8 + 256, stream);
        conv1_f64<<<gconv, 256, 0, stream>>>(feats, W1, in1, om1, bufA);
        bn_stats_f64<<<1024, 256, 0, stream>>>(bufA, stats);
        bn_apply<true><<<gelem, 256, 0, stream>>>(bufA, h1, stats, gamma1, beta1);
        // re-zero accumulator (and stats tail for BN2 reuse)
        hipMemsetAsync(d_ws, 0, BUF * 8 + 256, stream);
        conv2_f64<float><<<gconv, 256, 0, stream>>>(h1, W2, in2, om2, bufA);
        bn_stats_f64<<<1024, 256, 0, stream>>>(bufA, stats);
        final_f64<<<grow, 256, 0, stream>>>(bufA, stats, gamma2, beta2,
                                            Wcls, bcls, (float*)d_out);
    }
}